// Round 17
// baseline (312.364 us; speedup 1.0000x reference)
//
#include <hip/hip_runtime.h>

// LTLIF(tau=2, decay_input=False, hard reset) -> Linear -> BN, x2 blocks, +skip.
// T=128, B=256, C=512. GEMMs: M=T*B=32768, K=N=512.
//
// Round 13: exact i8-limb GEMM (4 limbs @2^32, i32 accum exact, f64 combine).
// R4-R12: six schedule variants all 64-87us @ MfmaUtil 15-20% -> the shared
// invariant (block barriers around a shared-LDS B stage) is the defect:
// 12 waves/CU in lockstep convoy; LDS ~1500cy and MFMA ~980cy per CU-iter,
// neither saturated, iter ~3600cy. Fix: NO BARRIERS, NO LDS. Fully
// independent waves, tile 64Mx16Nx4limbs (acc 64 regs); A AND B stream
// L2->reg with 1-iter register dbuf -- the compiler's dependency-driven
// waitcnt then equals counted vmcnt(8) and prefetch stays in flight across
// the MFMA cluster (this is what R5 lacked: it consumed in-iter). W limbs
// (1MB) are L2-resident; 4 waves/block share one bm (A panel L1-reused 4x);
// XCD partition keeps each S slice (2MB) L2-resident. Limb combine is
// in-register (R10 math, bit-identical). Stats written per-wave, no LDS.

typedef int i32x4 __attribute__((ext_vector_type(4)));

#define T_STEPS 128
#define BATCH   256
#define CH      512
#define BC      (BATCH * CH)        // 131072
#define MROWS   (T_STEPS * BATCH)   // 32768

// ---------------- W f32 -> 4 signed i8 limb planes (fixed point, scale 2^32) -
__global__ __launch_bounds__(256) void k_convw(const float* __restrict__ W0,
                                               const float* __restrict__ W1,
                                               signed char* __restrict__ WL0,
                                               signed char* __restrict__ WL1) {
  int b = blockIdx.x;                       // 2048 blocks: 1024 per matrix
  const float* W = (b < 1024) ? W0 : W1;
  signed char* WL = (b < 1024) ? WL0 : WL1;
  int i = (b & 1023) * 256 + threadIdx.x;   // 262144
  double z = (double)W[i] * 4294967296.0;
  z = fmin(fmax(z, -2147483647.0), 2147483647.0);  // safety clamp (never hit)
  int q = (int)llrint(z);
  int r = q;
  signed char l0 = (signed char)r; r = (r - l0) >> 8;
  signed char l1 = (signed char)r; r = (r - l1) >> 8;
  signed char l2 = (signed char)r; r = (r - l2) >> 8;
  signed char l3 = (signed char)r;
  WL[i]          = l0;
  WL[i + 262144] = l1;
  WL[i + 524288] = l2;
  WL[i + 786432] = l3;
}

// ---------------- LIF scan, block 1: x -> spikes (f32, bit-exact) -----------
__global__ __launch_bounds__(64) void k_lif1(const float* __restrict__ X,
                                             const float* __restrict__ wp,
                                             signed char* __restrict__ S) {
  int i = blockIdx.x * 64 + threadIdx.x;    // 0..BC-1
  float om = 1.0f - 1.0f / (1.0f + expf(-wp[0]));   // 0.5 exact
  float v = 0.0f;
  #pragma unroll 8
  for (int t = 0; t < T_STEPS; ++t) {
    float xt = X[(size_t)t * BC + i];
    v = v * om + xt;
    bool sp = (v >= 1.0f);
    S[(size_t)t * BC + i] = sp;
    v = sp ? 0.0f : v;
  }
}

// ---------------- LIF scan, block 2: h = f32(f64(y)*a+b) -> spikes ----------
__global__ __launch_bounds__(64) void k_lif2(const float* __restrict__ Y,
                                             const double* __restrict__ sA,
                                             const double* __restrict__ sB,
                                             const float* __restrict__ wp,
                                             signed char* __restrict__ S) {
  int i = blockIdx.x * 64 + threadIdx.x;
  int c = i & (CH - 1);
  double a = sA[c], b = sB[c];
  float om = 1.0f - 1.0f / (1.0f + expf(-wp[0]));
  float v = 0.0f;
  #pragma unroll 8
  for (int t = 0; t < T_STEPS; ++t) {
    float h = (float)((double)Y[(size_t)t * BC + i] * a + b);
    v = v * om + h;
    bool sp = (v >= 1.0f);
    S[(size_t)t * BC + i] = sp;
    v = sp ? 0.0f : v;
  }
}

// ---------------- i8 limb GEMM + fused BN partial stats ----------------------
// Independent waves: tile 64(M) x 16(N) x 4 limbs per wave; acc[4][4]=64 regs.
// A and B both L2->register with 1-iter dbuf prefetch; no LDS; no barriers.
// Fragment mapping (R4..R12-verified): lane holds 16 i8 of row (lane&15)+16m
// at k-bytes [lg*16, +16); C/D col=lane&15, row=(lane>>4)*4+q (+16m).
__global__ __launch_bounds__(256, 3) void k_gemm(const signed char* __restrict__ S,
                                                 const signed char* __restrict__ WL,
                                                 float* __restrict__ Y,
                                                 double* __restrict__ sumP,
                                                 double* __restrict__ sqP) {
  const int tid  = threadIdx.x;
  const int wid  = tid >> 6;
  const int lane = tid & 63;
  // XCD partition: xcd = bid&7. Each XCD owns bm in [xcd*64, xcd*64+64)
  // -> 2 MB S slice resident in its L2. Block = 4 waves, same bm (A panel
  // L1-reused 4x), wave-private bn = bg*4 + wid.
  const int bid   = blockIdx.x;                // 0..4095
  const int xcd   = bid & 7;
  const int local = bid >> 3;                  // 0..511
  const int bg    = local & 7;                 // 0..7
  const int bm    = xcd * 64 + (local >> 3);   // 0..511 (M/64)
  const int m0 = bm * 64;
  const int n0 = (bg * 4 + wid) * 16;          // 0..496 (N/16, per wave)
  const int lr = lane & 15, lg = lane >> 4;

  i32x4 acc[4][4] = {};   // [m-frag][limb] = 64 regs

  // A: row (m0 + lr + 16m), bytes [kt + lg*16, +16)  (16 full 64B lines/load)
  const signed char* aP = S  + (size_t)(m0 + lr) * 512 + lg * 16;
  // B: limb plane j, row (n0 + lr), same byte pattern
  const signed char* bP = WL + (size_t)(n0 + lr) * 512 + lg * 16;

  i32x4 aR[2][4], bR[2][4];
  #pragma unroll
  for (int m = 0; m < 4; ++m)
    aR[0][m] = *(const i32x4*)(aP + m * 8192);
  #pragma unroll
  for (int j = 0; j < 4; ++j)
    bR[0][j] = *(const i32x4*)(bP + (size_t)j * 262144);

  #pragma unroll
  for (int i = 0; i < 8; ++i) {
    const int cur = i & 1, nxt = cur ^ 1;
    if (i < 7) {   // prefetch next K-step: 8 loads stay in flight over MFMAs
      #pragma unroll
      for (int m = 0; m < 4; ++m)
        aR[nxt][m] = *(const i32x4*)(aP + m * 8192 + (i + 1) * 64);
      #pragma unroll
      for (int j = 0; j < 4; ++j)
        bR[nxt][j] = *(const i32x4*)(bP + (size_t)j * 262144 + (i + 1) * 64);
    }
    __builtin_amdgcn_sched_barrier(0);   // pin: prefetch issued before MFMAs

    __builtin_amdgcn_s_setprio(1);
    #pragma unroll
    for (int j = 0; j < 4; ++j)
      #pragma unroll
      for (int m = 0; m < 4; ++m)
        acc[m][j] = __builtin_amdgcn_mfma_i32_16x16x64_i8(
            aR[cur][m], bR[cur][j], acc[m][j], 0, 0, 0);
    __builtin_amdgcn_s_setprio(0);
  }

  // ---- epilogue: exact in-register limb combine, Y write, BN partials ------
  // C/D: col = lane&15, row = (lane>>4)*4 + q (+16m)
  const int r0 = m0 + lg * 4;
  double s = 0, q = 0;
  #pragma unroll
  for (int m = 0; m < 4; ++m)
    #pragma unroll
    for (int qi = 0; qi < 4; ++qi) {
      double yv = (((double)acc[m][3][qi] * 256.0 + (double)acc[m][2][qi]) * 256.0
                   + (double)acc[m][1][qi]) * 256.0 + (double)acc[m][0][qi];
      float yf = (float)(yv * 0x1p-32);
      Y[(size_t)(r0 + m * 16 + qi) * 512 + n0 + lr] = yf;
      double yd = (double)yf;
      s += yd; q += yd * yd;
    }
  // column sums: lanes {lr, lr+16, lr+32, lr+48} hold disjoint row groups
  s += __shfl_xor(s, 16); s += __shfl_xor(s, 32);
  q += __shfl_xor(q, 16); q += __shfl_xor(q, 32);
  if (lane < 16) {                      // channel = n0 + lane; fixed order
    sumP[(size_t)(n0 + lane) * 512 + bm] = s;
    sqP [(size_t)(n0 + lane) * 512 + bm] = q;
  }
}

// ---------------- BN stats stage 2: per-channel a, b (tree, deterministic) --
__global__ __launch_bounds__(256) void k_stats2(const double* __restrict__ sumP,
                                                const double* __restrict__ sqP,
                                                const float* __restrict__ gamma,
                                                const float* __restrict__ beta,
                                                double* __restrict__ sA,
                                                double* __restrict__ sB) {
  __shared__ double shS[256], shQ[256];
  int c = blockIdx.x;       // 512 blocks, one channel each
  int t = threadIdx.x;      // 512 partials, 2 per thread, coalesced
  shS[t] = sumP[(size_t)c * 512 + t] + sumP[(size_t)c * 512 + t + 256];
  shQ[t] = sqP [(size_t)c * 512 + t] + sqP [(size_t)c * 512 + t + 256];
  __syncthreads();
  for (int w = 128; w >= 1; w >>= 1) {
    if (t < w) { shS[t] += shS[t + w]; shQ[t] += shQ[t + w]; }
    __syncthreads();
  }
  if (t == 0) {
    const double invN = 1.0 / 32768.0;
    double mean = shS[0] * invN;
    double var  = shQ[0] * invN - mean * mean;
    double rstd = rsqrt(var + 1e-5);
    double a = (double)gamma[c] * rstd;
    sA[c] = a;
    sB[c] = (double)beta[c] - mean * a;
  }
}

// ---------------- final: out = f32(f64(y)*a + b + x) ------------------------
__global__ __launch_bounds__(256) void k_final(float* __restrict__ Y,
                                               const float* __restrict__ X,
                                               const double* __restrict__ sA,
                                               const double* __restrict__ sB) {
  size_t i = (size_t)blockIdx.x * 256 + threadIdx.x;  // float4 index
  int c0 = (int)((i * 4) & (CH - 1));
  float4 y = ((const float4*)Y)[i];
  float4 x = ((const float4*)X)[i];
  float4 o;
  o.x = (float)((double)y.x * sA[c0 + 0] + sB[c0 + 0] + (double)x.x);
  o.y = (float)((double)y.y * sA[c0 + 1] + sB[c0 + 1] + (double)x.y);
  o.z = (float)((double)y.z * sA[c0 + 2] + sB[c0 + 2] + (double)x.z);
  o.w = (float)((double)y.w * sA[c0 + 3] + sB[c0 + 3] + (double)x.w);
  ((float4*)Y)[i] = o;
}

// ---------------- launch ----------------------------------------------------
extern "C" void kernel_launch(void* const* d_in, const int* in_sizes, int n_in,
                              void* d_out, int out_size, void* d_ws, size_t ws_size,
                              hipStream_t stream) {
  (void)in_sizes; (void)n_in; (void)out_size; (void)ws_size;

  const float* x   = (const float*)d_in[0];
  const float* w0  = (const float*)d_in[1];
  const float* W0  = (const float*)d_in[2];
  // d_in[3] = b0: absorbed by BN
  const float* g0  = (const float*)d_in[4];
  const float* be0 = (const float*)d_in[5];
  const float* w1  = (const float*)d_in[6];
  const float* W1  = (const float*)d_in[7];
  // d_in[8] = b1: absorbed by BN
  const float* g1  = (const float*)d_in[9];
  const float* be1 = (const float*)d_in[10];
  float* Y = (float*)d_out;   // y1, then y2, then final output

  char* ws = (char*)d_ws;
  signed char* WL0  = (signed char*)(ws + 0x0000000);  // 1 MB (4 planes)
  signed char* WL1  = (signed char*)(ws + 0x0100000);  // 1 MB
  signed char* spk  = (signed char*)(ws + 0x0200000);  // 16.78 MB
  double*      sumP = (double*)(ws + 0x1200000);       // 2 MB [512][512]
  double*      sqP  = (double*)(ws + 0x1400000);       // 2 MB
  double*      sA   = (double*)(ws + 0x1600000);       // 4 KB
  double*      sB   = (double*)(ws + 0x1602000);       // 4 KB

  k_convw<<<2048, 256, 0, stream>>>(W0, W1, WL0, WL1);

  // block 1
  k_lif1 <<<BC / 64, 64, 0, stream>>>(x, w0, spk);
  k_gemm <<<(MROWS / 64) * (CH / 64), 256, 0, stream>>>(spk, WL0, Y, sumP, sqP);
  k_stats2<<<512, 256, 0, stream>>>(sumP, sqP, g0, be0, sA, sB);

  // block 2 (BN affine of block 1 fused into LIF input, f64->f32 once)
  k_lif2 <<<BC / 64, 64, 0, stream>>>(Y, sA, sB, w1, spk);
  k_gemm <<<(MROWS / 64) * (CH / 64), 256, 0, stream>>>(spk, WL1, Y, sumP, sqP);
  k_stats2<<<512, 256, 0, stream>>>(sumP, sqP, g1, be1, sA, sB);

  // out = BN(y2) + x
  k_final<<<(MROWS * CH) / (4 * 256), 256, 0, stream>>>(Y, x, sA, sB);
}

// Round 18
// 208.049 us; speedup vs baseline: 1.5014x; 1.5014x over previous
//
#include <hip/hip_runtime.h>

// LTLIF(tau=2, decay_input=False, hard reset) -> Linear -> BN, x2 blocks, +skip.
// T=128, B=256, C=512. GEMMs: M=T*B=32768, K=N=512.
//
// Round 14: exact i8-limb GEMM (4 limbs @2^32, i32 accum exact, f64 combine).
// Evidence: LDS+per-iter-barriers = 64-87us @15-20% MfmaUtil (R4-R12);
// no-LDS reg streaming = 125-148us @9-11% (R5/R13). New structure = LDS-
// shared B WITHOUT inner barriers: the whole B panel for a 32-col slice is
// 4limbs x 32 x 512 = 64 KB -> stage ONCE, one __syncthreads, then 64
// barrier-free iterations (8 m-tiles x 8 K-steps) with B read-only in LDS
// and A streamed L2->reg with continuous 1-ahead prefetch. No waitcnt
// fences needed: compiler counts lgkmcnt/vmcnt by dependency (good in the
// no-barrier regime, m97). Swizzle for [limb][32][512]: granule ^= row&7,
// applied both sides (pre-swizzled stage source + swizzled read). Block =
// 4 waves (2M x 2N), wave tile 32M x 16N x 4 limbs (acc 32 regs), 512-row
// M-slice per block, grid 1024, 2 blocks/CU (64KB LDS), 2 waves/SIMD.
// XCD partition: xcd owns 8 mg-slices (2MB S, L2-resident) x all 16 bn.

typedef int i32x4 __attribute__((ext_vector_type(4)));

#define T_STEPS 128
#define BATCH   256
#define CH      512
#define BC      (BATCH * CH)        // 131072
#define MROWS   (T_STEPS * BATCH)   // 32768

// ---------------- async global->LDS (16B per lane, wave-uniform LDS base) ----
__device__ __forceinline__ void llds16(const void* g, void* l) {
  __builtin_amdgcn_global_load_lds(
      (const __attribute__((address_space(1))) void*)g,
      (__attribute__((address_space(3))) void*)l, 16, 0, 0);
}

// ---------------- W f32 -> 4 signed i8 limb planes (fixed point, scale 2^32) -
__global__ __launch_bounds__(256) void k_convw(const float* __restrict__ W0,
                                               const float* __restrict__ W1,
                                               signed char* __restrict__ WL0,
                                               signed char* __restrict__ WL1) {
  int b = blockIdx.x;                       // 2048 blocks: 1024 per matrix
  const float* W = (b < 1024) ? W0 : W1;
  signed char* WL = (b < 1024) ? WL0 : WL1;
  int i = (b & 1023) * 256 + threadIdx.x;   // 262144
  double z = (double)W[i] * 4294967296.0;
  z = fmin(fmax(z, -2147483647.0), 2147483647.0);  // safety clamp (never hit)
  int q = (int)llrint(z);
  int r = q;
  signed char l0 = (signed char)r; r = (r - l0) >> 8;
  signed char l1 = (signed char)r; r = (r - l1) >> 8;
  signed char l2 = (signed char)r; r = (r - l2) >> 8;
  signed char l3 = (signed char)r;
  WL[i]          = l0;
  WL[i + 262144] = l1;
  WL[i + 524288] = l2;
  WL[i + 786432] = l3;
}

// ---------------- LIF scan, block 1: x -> spikes (f32, bit-exact) -----------
__global__ __launch_bounds__(64) void k_lif1(const float* __restrict__ X,
                                             const float* __restrict__ wp,
                                             signed char* __restrict__ S) {
  int i = blockIdx.x * 64 + threadIdx.x;    // 0..BC-1
  float om = 1.0f - 1.0f / (1.0f + expf(-wp[0]));   // 0.5 exact
  float v = 0.0f;
  #pragma unroll 8
  for (int t = 0; t < T_STEPS; ++t) {
    float xt = X[(size_t)t * BC + i];
    v = v * om + xt;
    bool sp = (v >= 1.0f);
    S[(size_t)t * BC + i] = sp;
    v = sp ? 0.0f : v;
  }
}

// ---------------- LIF scan, block 2: h = f32(f64(y)*a+b) -> spikes ----------
__global__ __launch_bounds__(64) void k_lif2(const float* __restrict__ Y,
                                             const double* __restrict__ sA,
                                             const double* __restrict__ sB,
                                             const float* __restrict__ wp,
                                             signed char* __restrict__ S) {
  int i = blockIdx.x * 64 + threadIdx.x;
  int c = i & (CH - 1);
  double a = sA[c], b = sB[c];
  float om = 1.0f - 1.0f / (1.0f + expf(-wp[0]));
  float v = 0.0f;
  #pragma unroll 8
  for (int t = 0; t < T_STEPS; ++t) {
    float h = (float)((double)Y[(size_t)t * BC + i] * a + b);
    v = v * om + h;
    bool sp = (v >= 1.0f);
    S[(size_t)t * BC + i] = sp;
    v = sp ? 0.0f : v;
  }
}

// ---------------- i8 limb GEMM + fused BN partial stats ----------------------
// Block: 32 N-cols x 512 M-rows x full K=512. B panel resident in LDS
// (64 KB, staged once). 4 waves (wm=M-half of each 64-row tile, wn=N-half).
// Wave tile 32M x 16N x 4 limbs; acc[2][4] = 32 regs. 64 barrier-free
// iterations; A: L2->reg 1-ahead prefetch crossing m-tile boundaries.
__global__ __launch_bounds__(256, 2) void k_gemm(const signed char* __restrict__ S,
                                                 const signed char* __restrict__ WL,
                                                 float* __restrict__ Y,
                                                 double* __restrict__ sumP,
                                                 double* __restrict__ sqP) {
  __shared__ __align__(16) signed char Bp[4][32][512];   // 64 KB, full B panel

  const int tid  = threadIdx.x;
  const int wid  = tid >> 6;
  const int lane = tid & 63;
  // bid (0..1023) -> xcd = bid&7; rest: bn (16) fast, mg-local (8) slow.
  // XCD owns mg in [xcd*8, xcd*8+8) -> 8 x 256KB = 2MB S slice, L2-resident,
  // reused by its 16 bn-sibling groups.
  const int bid  = blockIdx.x;
  const int xcd  = bid & 7;
  const int rest = bid >> 3;                   // 0..127
  const int bn   = rest & 15;                  // 0..15  (N/32)
  const int mg   = xcd * 8 + (rest >> 4);      // 0..63  (M/512)
  const int n0    = bn * 32;
  const int mBase = mg * 512;
  const int wm = wid >> 1, wn = wid & 1;
  const int lr = lane & 15, lg = lane >> 4;

  // ---- stage full B panel: 4096 chunks of 16B, 16 per thread --------------
  // chunk cid = limb*1024 + row*32 + gl; LDS linear at cid*16; source granule
  // pre-swizzled gg = gl ^ (row&7)  (both-sides rule).
  #pragma unroll
  for (int p = 0; p < 16; ++p) {
    int cid  = p * 256 + tid;
    int limb = cid >> 10;
    int row  = (cid >> 5) & 31;
    int gl   = cid & 31;
    int gg   = gl ^ (row & 7);
    llds16(WL + (size_t)limb * 262144 + (size_t)(n0 + row) * 512 + gg * 16,
           (char*)Bp + p * 4096 + wid * 1024);
  }

  // A prefetch for iteration 0 (can overlap the stage)
  i32x4 a[2][2];
  {
    const signed char* ap = S + (size_t)(mBase + wm * 32 + lr) * 512 + lg * 16;
    a[0][0] = *(const i32x4*)ap;
    a[0][1] = *(const i32x4*)(ap + 8192);
  }
  __syncthreads();   // single barrier: B panel published (vmcnt drained once)

  const signed char* BpF = (const signed char*)Bp;
  const int brow  = wn * 16 + lr;              // this lane's B row (channel)
  const unsigned bbase = (unsigned)(brow * 512);
  const int rswz  = brow & 7;

  double s = 0.0, qsum = 0.0;                  // per-lane BN partials

  for (int si = 0; si < 8; ++si) {             // 8 m-tiles of 64 rows
    i32x4 acc[2][4] = {};                      // [m-frag][limb] = 32 regs
    #pragma unroll
    for (int kt = 0; kt < 8; ++kt) {
      const int it  = si * 8 + kt;
      const int cur = it & 1;
      if (it < 63) {                           // continuous 1-ahead A prefetch
        const int nit = it + 1, nsi = nit >> 3, nkt = nit & 7;
        const signed char* ap = S + (size_t)(mBase + nsi * 64 + wm * 32 + lr) * 512
                                  + nkt * 64 + lg * 16;
        a[cur ^ 1][0] = *(const i32x4*)ap;
        a[cur ^ 1][1] = *(const i32x4*)(ap + 8192);
      }
      // B: 4 limb fragments from read-only LDS (swizzled granule)
      const unsigned gs = bbase + (unsigned)((((kt * 4 + lg) ^ rswz)) * 16);
      i32x4 b0 = *(const i32x4*)(BpF + gs);
      i32x4 b1 = *(const i32x4*)(BpF + gs + 16384);
      i32x4 b2 = *(const i32x4*)(BpF + gs + 32768);
      i32x4 b3 = *(const i32x4*)(BpF + gs + 49152);

      acc[0][0] = __builtin_amdgcn_mfma_i32_16x16x64_i8(a[cur][0], b0, acc[0][0], 0, 0, 0);
      acc[1][0] = __builtin_amdgcn_mfma_i32_16x16x64_i8(a[cur][1], b0, acc[1][0], 0, 0, 0);
      acc[0][1] = __builtin_amdgcn_mfma_i32_16x16x64_i8(a[cur][0], b1, acc[0][1], 0, 0, 0);
      acc[1][1] = __builtin_amdgcn_mfma_i32_16x16x64_i8(a[cur][1], b1, acc[1][1], 0, 0, 0);
      acc[0][2] = __builtin_amdgcn_mfma_i32_16x16x64_i8(a[cur][0], b2, acc[0][2], 0, 0, 0);
      acc[1][2] = __builtin_amdgcn_mfma_i32_16x16x64_i8(a[cur][1], b2, acc[1][2], 0, 0, 0);
      acc[0][3] = __builtin_amdgcn_mfma_i32_16x16x64_i8(a[cur][0], b3, acc[0][3], 0, 0, 0);
      acc[1][3] = __builtin_amdgcn_mfma_i32_16x16x64_i8(a[cur][1], b3, acc[1][3], 0, 0, 0);
    }

    // ---- per-m-tile epilogue: exact limb combine, Y write, stats ----------
    // C/D: col = lane&15, row = (lane>>4)*4 + q (+16m)
    const int r0 = mBase + si * 64 + wm * 32 + lg * 4;
    #pragma unroll
    for (int m = 0; m < 2; ++m)
      #pragma unroll
      for (int qi = 0; qi < 4; ++qi) {
        double yv = (((double)acc[m][3][qi] * 256.0 + (double)acc[m][2][qi]) * 256.0
                     + (double)acc[m][1][qi]) * 256.0 + (double)acc[m][0][qi];
        float yf = (float)(yv * 0x1p-32);
        Y[(size_t)(r0 + m * 16 + qi) * 512 + n0 + brow] = yf;
        double yd = (double)yf;
        s += yd; qsum += yd * yd;
      }
  }

  // column sums: lanes {lr, lr+16, lr+32, lr+48} hold disjoint row groups
  s    += __shfl_xor(s, 16);    s    += __shfl_xor(s, 32);
  qsum += __shfl_xor(qsum, 16); qsum += __shfl_xor(qsum, 32);

  // cross-wave (wm) combine via LDS (B panel dead), fixed order
  __syncthreads();
  double* sh = (double*)Bp;       // [0..63]=s slots, [64..127]=q slots
  if (lane < 16) {
    sh[wm * 32 + wn * 16 + lane]      = s;
    sh[64 + wm * 32 + wn * 16 + lane] = qsum;
  }
  __syncthreads();
  if (tid < 32) {                  // local channel = tid
    sumP[(size_t)(n0 + tid) * 64 + mg] = sh[tid] + sh[32 + tid];
    sqP [(size_t)(n0 + tid) * 64 + mg] = sh[64 + tid] + sh[96 + tid];
  }
}

// ---------------- BN stats stage 2: per-channel a, b (wave tree) ------------
__global__ __launch_bounds__(64) void k_stats2(const double* __restrict__ sumP,
                                               const double* __restrict__ sqP,
                                               const float* __restrict__ gamma,
                                               const float* __restrict__ beta,
                                               double* __restrict__ sA,
                                               double* __restrict__ sB) {
  int c = blockIdx.x;       // 512 blocks, one channel each
  int t = threadIdx.x;      // 64 partials, coalesced
  double s = sumP[(size_t)c * 64 + t];
  double q = sqP [(size_t)c * 64 + t];
  #pragma unroll
  for (int off = 32; off >= 1; off >>= 1) {   // fixed order: deterministic
    s += __shfl_down(s, off);
    q += __shfl_down(q, off);
  }
  if (t == 0) {
    const double invN = 1.0 / 32768.0;
    double mean = s * invN;
    double var  = q * invN - mean * mean;
    double rstd = rsqrt(var + 1e-5);
    double a = (double)gamma[c] * rstd;
    sA[c] = a;
    sB[c] = (double)beta[c] - mean * a;
  }
}

// ---------------- final: out = f32(f64(y)*a + b + x) ------------------------
__global__ __launch_bounds__(256) void k_final(float* __restrict__ Y,
                                               const float* __restrict__ X,
                                               const double* __restrict__ sA,
                                               const double* __restrict__ sB) {
  size_t i = (size_t)blockIdx.x * 256 + threadIdx.x;  // float4 index
  int c0 = (int)((i * 4) & (CH - 1));
  float4 y = ((const float4*)Y)[i];
  float4 x = ((const float4*)X)[i];
  float4 o;
  o.x = (float)((double)y.x * sA[c0 + 0] + sB[c0 + 0] + (double)x.x);
  o.y = (float)((double)y.y * sA[c0 + 1] + sB[c0 + 1] + (double)x.y);
  o.z = (float)((double)y.z * sA[c0 + 2] + sB[c0 + 2] + (double)x.z);
  o.w = (float)((double)y.w * sA[c0 + 3] + sB[c0 + 3] + (double)x.w);
  ((float4*)Y)[i] = o;
}

// ---------------- launch ----------------------------------------------------
extern "C" void kernel_launch(void* const* d_in, const int* in_sizes, int n_in,
                              void* d_out, int out_size, void* d_ws, size_t ws_size,
                              hipStream_t stream) {
  (void)in_sizes; (void)n_in; (void)out_size; (void)ws_size;

  const float* x   = (const float*)d_in[0];
  const float* w0  = (const float*)d_in[1];
  const float* W0  = (const float*)d_in[2];
  // d_in[3] = b0: absorbed by BN
  const float* g0  = (const float*)d_in[4];
  const float* be0 = (const float*)d_in[5];
  const float* w1  = (const float*)d_in[6];
  const float* W1  = (const float*)d_in[7];
  // d_in[8] = b1: absorbed by BN
  const float* g1  = (const float*)d_in[9];
  const float* be1 = (const float*)d_in[10];
  float* Y = (float*)d_out;   // y1, then y2, then final output

  char* ws = (char*)d_ws;
  signed char* WL0  = (signed char*)(ws + 0x0000000);  // 1 MB (4 planes)
  signed char* WL1  = (signed char*)(ws + 0x0100000);  // 1 MB
  signed char* spk  = (signed char*)(ws + 0x0200000);  // 16.78 MB
  double*      sumP = (double*)(ws + 0x1200000);       // 256 KB [512][64]
  double*      sqP  = (double*)(ws + 0x1240000);       // 256 KB
  double*      sA   = (double*)(ws + 0x1280000);       // 4 KB
  double*      sB   = (double*)(ws + 0x1282000);       // 4 KB

  k_convw<<<2048, 256, 0, stream>>>(W0, W1, WL0, WL1);

  // block 1
  k_lif1 <<<BC / 64, 64, 0, stream>>>(x, w0, spk);
  k_gemm <<<(MROWS / 512) * (CH / 32), 256, 0, stream>>>(spk, WL0, Y, sumP, sqP);
  k_stats2<<<512, 64, 0, stream>>>(sumP, sqP, g0, be0, sA, sB);

  // block 2 (BN affine of block 1 fused into LIF input, f64->f32 once)
  k_lif2 <<<BC / 64, 64, 0, stream>>>(Y, sA, sB, w1, spk);
  k_gemm <<<(MROWS / 512) * (CH / 32), 256, 0, stream>>>(spk, WL1, Y, sumP, sqP);
  k_stats2<<<512, 64, 0, stream>>>(sumP, sqP, g1, be1, sA, sB);

  // out = BN(y2) + x
  k_final<<<(MROWS * CH) / (4 * 256), 256, 0, stream>>>(Y, x, sA, sB);
}